// Round 1
// baseline (438.620 us; speedup 1.0000x reference)
//
#include <hip/hip_runtime.h>
#include <math.h>

// KinematicLayer: B=524288 trajectories, T=64 steps.
// psi is a linear recurrence -> prefix-sum; x,y are prefix sums of dx,dy.
// Mapping: 16 lanes per trajectory, 4 timesteps/lane (float4 I/O),
// segmented shuffle scans (width 16). Fully coalesced global access.

#define T_STEPS 64

__global__ __launch_bounds__(256) void kin_scan_kernel(
    const float* __restrict__ speed,
    const float* __restrict__ yaw,
    const float* __restrict__ init_pos,
    const float* __restrict__ init_heading,
    float* __restrict__ out,
    int B)
{
    const float DT    = 0.1f;
    const float IMG_W = 1920.0f;
    const float IMG_H = 1080.0f;
    const float DIAG  = 2202.9071700822459f;  // sqrt(1920^2+1080^2), rounds like ref
    const float INV_W = 1.0f / 1920.0f;
    const float INV_H = 1.0f / 1080.0f;

    const int tid = blockIdx.x * blockDim.x + threadIdx.x;
    const int row = tid >> 4;          // one trajectory per 16 lanes
    if (row >= B) return;
    const int seg = tid & 15;          // lane within the 16-lane segment
    const int t0  = seg * 4;           // first timestep this lane owns

    // ---- coalesced loads: 4 consecutive timesteps per lane ----
    const float4* sp4 = reinterpret_cast<const float4*>(speed) + (size_t)row * 16 + seg;
    const float4* yw4 = reinterpret_cast<const float4*>(yaw)   + (size_t)row * 16 + seg;
    float4 v4 = *sp4;
    float4 w4 = *yw4;

    // ---- yaw decay 0.97^t ----
    float d  = powf(0.97f, (float)t0);
    float w0 = w4.x * d; d *= 0.97f;
    float w1 = w4.y * d; d *= 0.97f;
    float w2 = w4.z * d; d *= 0.97f;
    float w3 = w4.w * d;

    // ---- psi scan: local sum then segmented exclusive scan over 16 lanes ----
    float wl = ((w0 + w1) + w2) + w3;
    float s  = wl;
    #pragma unroll
    for (int dlt = 1; dlt < 16; dlt <<= 1) {
        float o = __shfl_up(s, (unsigned)dlt, 16);
        if (seg >= dlt) s += o;
    }
    float wexcl = s - wl;  // sum of w over all timesteps before t0 (seg==0 -> exactly 0)

    const float psi0 = init_heading[row];
    const float2 ip  = reinterpret_cast<const float2*>(init_pos)[row];
    const float x0   = ip.x * IMG_W;
    const float y0   = ip.y * IMG_H;

    float p = psi0 + DT * wexcl;       // psi at timestep t0 (pre-update)
    float sp, cp;
    sincosf(p, &sp, &cp);

    // ---- 4 steps: dx/dy via carried sincos ----
    float dx[4], dy[4];
    float wv[4] = {w0, w1, w2, w3};
    float vv[4] = {v4.x * DIAG, v4.y * DIAG, v4.z * DIAG, v4.w * DIAG};
    #pragma unroll
    for (int j = 0; j < 4; ++j) {
        float v = vv[j];
        float w = wv[j];
        float pn = p + w * DT;
        float sn, cn;
        sincosf(pn, &sn, &cn);
        bool  is_str = fabsf(w) < 0.01f;
        float w_safe = w + (is_str ? 1e-4f : 0.0f);
        float r   = v / w_safe;
        float dxs = v * cp * DT;
        float dys = v * sp * DT;
        float dxt = r * (sn - sp);
        float dyt = -r * (cn - cp);
        dx[j] = is_str ? dxs : dxt;
        dy[j] = is_str ? dys : dyt;
        p = pn; sp = sn; cp = cn;
    }

    // ---- local inclusive prefix of dx/dy ----
    float xi0 = dx[0];
    float xi1 = xi0 + dx[1];
    float xi2 = xi1 + dx[2];
    float xi3 = xi2 + dx[3];
    float yi0 = dy[0];
    float yi1 = yi0 + dy[1];
    float yi2 = yi1 + dy[2];
    float yi3 = yi2 + dy[3];

    // ---- segmented exclusive scans for x and y (interleaved) ----
    float xs = xi3, ys = yi3;
    #pragma unroll
    for (int dlt = 1; dlt < 16; dlt <<= 1) {
        float ox = __shfl_up(xs, (unsigned)dlt, 16);
        float oy = __shfl_up(ys, (unsigned)dlt, 16);
        if (seg >= dlt) { xs += ox; ys += oy; }
    }
    float xb = (xs - xi3) + x0;   // x just before this lane's first step
    float yb = (ys - yi3) + y0;

    // ---- normalized outputs, coalesced float4 stores ----
    float4 o0, o1;
    o0.x = (xb + xi0) * INV_W;  o0.y = (yb + yi0) * INV_H;
    o0.z = (xb + xi1) * INV_W;  o0.w = (yb + yi1) * INV_H;
    o1.x = (xb + xi2) * INV_W;  o1.y = (yb + yi2) * INV_H;
    o1.z = (xb + xi3) * INV_W;  o1.w = (yb + yi3) * INV_H;

    float4* op = reinterpret_cast<float4*>(out) + (size_t)row * 32 + seg * 2;
    op[0] = o0;
    op[1] = o1;
}

extern "C" void kernel_launch(void* const* d_in, const int* in_sizes, int n_in,
                              void* d_out, int out_size, void* d_ws, size_t ws_size,
                              hipStream_t stream) {
    const float* speed        = (const float*)d_in[0];
    const float* yaw_rate     = (const float*)d_in[1];
    const float* init_pos     = (const float*)d_in[2];
    const float* init_heading = (const float*)d_in[3];
    float* out = (float*)d_out;

    const int B = in_sizes[3];                 // init_heading has B elements
    const int threads = 256;
    const int total   = B * 16;                // 16 lanes per trajectory
    const int blocks  = (total + threads - 1) / threads;

    kin_scan_kernel<<<blocks, threads, 0, stream>>>(
        speed, yaw_rate, init_pos, init_heading, out, B);
}